// Round 1
// baseline (224.075 us; speedup 1.0000x reference)
//
#include <hip/hip_runtime.h>
#include <math.h>

#define BATCH 16384

typedef float v2f __attribute__((ext_vector_type(2)));
typedef unsigned short u16;

__device__ __forceinline__ v2f pk_fma(v2f a, v2f b, v2f c) {
  return __builtin_elementwise_fma(a, b, c);   // -> v_pk_fma_f32
}
__device__ __forceinline__ v2f pk_max(v2f a, v2f b) {
  return __builtin_elementwise_max(a, b);      // -> v_pk_max_f32
}

// RNE-pack two floats into a bf16 pair (lo -> low16, hi -> high16), scalar path
__device__ __forceinline__ unsigned bf2(float lo, float hi) {
  unsigned a = __float_as_uint(lo);
  unsigned b = __float_as_uint(hi);
  a = (a + 0x7fffu + ((a >> 16) & 1u)) >> 16;
  b = (b + 0x7fffu + ((b >> 16) & 1u)) & 0xffff0000u;
  return a | b;
}

// single-inst RNE pack: dst.lo16 = bf16(lo), dst.hi16 = bf16(hi)
__device__ __forceinline__ unsigned cvtpk(float lo, float hi) {
  unsigned r;
  asm("v_cvt_pk_bf16_f32 %0, %1, %2" : "=v"(r) : "v"(lo), "v"(hi));
  return r;
}
__device__ __forceinline__ float blo(unsigned u) { return __uint_as_float(u << 16); }
__device__ __forceinline__ float bhi(unsigned u) { return __uint_as_float(u & 0xffff0000u); }

// v12: occupancy build. v8/v11 was triple-capped at 16 waves/CU (grid: 4096
// waves exact-fill; LDS: 38.4KB -> 4 blk/CU; VGPR: 72 > 64 cliff). This
// version: 2 samples/wave (grid 2048 blk = 8 blk/CU), bf16 h1/h2 LDS tiles
// (19.3KB -> 8 blk/CU), prefetch dropped + __launch_bounds__(256,8) to force
// VGPR<=64. TLP (8 waves/SIMD) replaces the ILP prefetch for latency hiding.
// Stage 2: 196-dot split across two 16-lane halves, combined via shfl_xor(16);
// circuit duplicated on the spare 16-lane groups (guarded writes).
__global__ __launch_bounds__(256, 8) void qnat_fused(
    const float* __restrict__ x,    // (B,1,28,28)
    const float* __restrict__ w1,   // (4,1,3,3)  uniform -> s_load
    const float* __restrict__ b1,   // (4,)
    const float* __restrict__ w2,   // (4,4,3,3)  uniform -> s_load
    const float* __restrict__ b2,   // (4,)
    const float* __restrict__ plw,  // (16,196)
    const float* __restrict__ plb,  // (16,)
    const float* __restrict__ rw,   // (4,4)
    const float* __restrict__ rb,   // (4,)
    float* __restrict__ pre,        // (B,4) pre-BN output (in d_out)
    float* __restrict__ stats)      // [8] {sum_c, sumsq_c}
{
  // per-wave h1 (bf16): 4 ch x (16 rows x 18 cols), ch stride 288 shorts.
  // data col c at stored c+1; rows 0,15 / cols 0,15 are persistent zero pads.
  __shared__ __align__(16) u16 h1s[4][4 * 288];
  // per-wave h2 (bf16): 2 sample slots x 208 shorts (196 data + 12 zero pad)
  __shared__ __align__(16) u16 h2s[4][2][208];
  // block-shared transposed bf16 plw: row t (f=8t..8t+7) x 16 k-cols; row 25 = 0
  __shared__ __align__(16) uint4 plw_tb[26 * 16];
  __shared__ float s_red[4][8];

  const int tid = threadIdx.x;
  const int w = tid >> 6;
  const int lane = tid & 63;
  const int base = (blockIdx.x * 4 + w) * 2;    // first of 2 samples

  // ---- stage plw -> plw_tb (bf16, transposed), once per block ----
  #pragma unroll
  for (int j = 0; j < 2; j++) {
    int s = tid + 256 * j;
    if (s < 416) {
      int tp = s >> 4;                // 0..25
      int k2 = s & 15;
      uint4 v = make_uint4(0u, 0u, 0u, 0u);
      if (tp < 25) {
        const float4* pr = (const float4*)(plw + k2 * 196);
        float4 a = pr[2 * tp];
        float4 b = (tp < 24) ? pr[2 * tp + 1] : make_float4(0.f, 0.f, 0.f, 0.f);
        v = make_uint4(bf2(a.x, a.y), bf2(a.z, a.w),
                       bf2(b.x, b.y), bf2(b.z, b.w));
      }
      plw_tb[s] = v;
    }
  }

  // ---- zero h1s fully + h2 tail pads (wave-private) ----
  {
    uint4 z4 = make_uint4(0u, 0u, 0u, 0u);
    uint4* hz = (uint4*)&h1s[w][0];             // 2304B = 144 uint4
    #pragma unroll
    for (int t = 0; t < 3; t++) {
      int p = t * 64 + lane;
      if (p < 144) hz[p] = z4;
    }
    if (lane < 4) {                              // shorts 192..207 of each slot
      uint4* hp4 = (uint4*)&h2s[w][lane >> 1][0];
      hp4[24 + (lane & 1)] = z4;
    }
  }
  __syncthreads();   // plw_tb visible

  const int i = lane >> 2;            // conv1: pooled row 0..13
  const int q = lane & 3;             // conv1: col quad
  const bool c1act = lane < 56;

  // ================= stage 1: conv both layers for 2 samples =================
  for (int it = 0; it < 2; ++it) {
    // ---- conv1 + relu + pool -> h1s (bf16) ----
    if (c1act) {
      float win[4][10];               // win[r][k] <-> input col 8q-1+k
      const float* xb = x + (size_t)(base + it) * 784;
      #pragma unroll
      for (int r = 0; r < 4; r++) {
        int row = 2 * i - 1 + r;
        if (0 <= row && row < 28) {
          const float* rp = xb + row * 28;
          win[r][0] = (q > 0) ? rp[8 * q - 1] : 0.0f;
          float4 a = *(const float4*)(rp + 8 * q);
          win[r][1] = a.x; win[r][2] = a.y; win[r][3] = a.z; win[r][4] = a.w;
          if (q < 3) {
            float4 b = *(const float4*)(rp + 8 * q + 4);
            win[r][5] = b.x; win[r][6] = b.y; win[r][7] = b.z; win[r][8] = b.w;
            win[r][9] = rp[8 * q + 8];
          } else {
            win[r][5] = 0.f; win[r][6] = 0.f; win[r][7] = 0.f;
            win[r][8] = 0.f; win[r][9] = 0.f;
          }
        } else {
          #pragma unroll
          for (int kk = 0; kk < 10; kk++) win[r][kk] = 0.0f;
        }
      }
      v2f P[4][9];
      #pragma unroll
      for (int r = 0; r < 4; r++)
        #pragma unroll
        for (int kk = 0; kk < 9; kk++) P[r][kk] = (v2f){win[r][kk], win[r][kk + 1]};

      u16* hb = &h1s[w][18 * (i + 1) + 1 + 4 * q];
      #pragma unroll
      for (int c = 0; c < 4; c++) {
        const float* wc = w1 + c * 9;
        const v2f bias2 = (v2f){b1[c], b1[c]};
        v2f a0[4], a1[4];
        #pragma unroll
        for (int jj = 0; jj < 4; jj++) { a0[jj] = bias2; a1[jj] = bias2; }
        #pragma unroll
        for (int dy = 0; dy < 3; dy++)
          #pragma unroll
          for (int dx = 0; dx < 3; dx++) {
            const float wv = wc[dy * 3 + dx];
            const v2f wvv = (v2f){wv, wv};
            #pragma unroll
            for (int jj = 0; jj < 4; jj++) {
              a0[jj] = pk_fma(P[dy][2 * jj + dx],     wvv, a0[jj]);
              a1[jj] = pk_fma(P[dy + 1][2 * jj + dx], wvv, a1[jj]);
            }
          }
        float m[4];
        #pragma unroll
        for (int jj = 0; jj < 4; jj++) {
          v2f mm = pk_max(a0[jj], a1[jj]);
          m[jj] = fmaxf(fmaxf(mm.x, mm.y), 0.0f);
        }
        u16* p = hb + 288 * c;
        if (q < 3) {
          unsigned u03 = cvtpk(m[0], m[3]);
          unsigned u12 = cvtpk(m[1], m[2]);
          p[0] = (u16)u03;
          *(unsigned*)(p + 1) = u12;             // short idx even -> 4B aligned
          p[3] = (u16)(u03 >> 16);
        } else {
          unsigned u01 = cvtpk(m[0], m[1]);
          p[0] = (u16)u01;
          p[1] = (u16)(u01 >> 16);
        }
      }
    }
    // h1s wave-private: no barrier.

    // ---- conv2 + relu + pool -> h2s[w][it] (bf16) ----
    {
      const int jq = lane & 7;
      const int i2 = lane >> 3;
      if (i2 < 7 && jq < 7) {
        v2f acc[4][2];
        #pragma unroll
        for (int co = 0; co < 4; co++) {
          const v2f bb = (v2f){b2[co], b2[co]};
          acc[co][0] = bb; acc[co][1] = bb;
        }
        #pragma unroll
        for (int ci = 0; ci < 4; ci++) {
          const u16* rp = &h1s[w][288 * ci + 36 * i2 + 2 * jq];
          v2f Q[4][3];
          #pragma unroll
          for (int r = 0; r < 4; r++) {
            unsigned u0 = *(const unsigned*)(rp + 18 * r);      // cols 2jq,2jq+1
            unsigned u1 = *(const unsigned*)(rp + 18 * r + 2);  // cols 2jq+2,2jq+3
            float f0 = blo(u0), f1 = bhi(u0), f2 = blo(u1), f3 = bhi(u1);
            Q[r][0] = (v2f){f0, f1};
            Q[r][1] = (v2f){f1, f2};
            Q[r][2] = (v2f){f2, f3};
          }
          #pragma unroll
          for (int co = 0; co < 4; co++) {
            const float* wp = w2 + (co * 4 + ci) * 9;
            #pragma unroll
            for (int dy = 0; dy < 3; dy++)
              #pragma unroll
              for (int dx = 0; dx < 3; dx++) {
                const float wv = wp[dy * 3 + dx];
                const v2f wvv = (v2f){wv, wv};
                acc[co][0] = pk_fma(Q[dy][dx],     wvv, acc[co][0]);
                acc[co][1] = pk_fma(Q[dy + 1][dx], wvv, acc[co][1]);
              }
          }
        }
        float mo[4];
        #pragma unroll
        for (int co = 0; co < 4; co++) {
          v2f mm = pk_max(acc[co][0], acc[co][1]);
          mo[co] = fmaxf(fmaxf(mm.x, mm.y), 0.0f);
        }
        unsigned u01 = cvtpk(mo[0], mo[1]);
        unsigned u23 = cvtpk(mo[2], mo[3]);
        u16* hp = &h2s[w][it][7 * i2 + jq];
        hp[0]   = (u16)u01;
        hp[49]  = (u16)(u01 >> 16);
        hp[98]  = (u16)u23;
        hp[147] = (u16)(u23 >> 16);
      }
    }
    // h2s wave-private: no barrier.
  }

  // ============ stage 2: linear + circuit, 2 samples, all 64 lanes ============
  const int s2 = lane >> 5;           // sample slot 0..1
  const int half = (lane >> 4) & 1;   // dot-product half
  const int k = lane & 15;            // param index / amp index

  // ---- linear: 196-dot split across two 16-lane halves; LDS-only operands ----
  float cv, sv;
  {
    const uint4* hb4 = (const uint4*)&h2s[w][s2][0];   // 26 uint4, broadcast
    const uint4* wb4 = &plw_tb[k];                     // row stride 16 uint4s
    v2f sacc = (v2f){0.0f, 0.0f};
    #pragma unroll
    for (int tt = 0; tt < 13; tt++) {
      int t = 2 * tt + half;                           // t=25 reads zero pad
      uint4 hb = hb4[t];
      uint4 wb = wb4[16 * t];
      sacc = pk_fma((v2f){blo(hb.x), bhi(hb.x)}, (v2f){blo(wb.x), bhi(wb.x)}, sacc);
      sacc = pk_fma((v2f){blo(hb.y), bhi(hb.y)}, (v2f){blo(wb.y), bhi(wb.y)}, sacc);
      sacc = pk_fma((v2f){blo(hb.z), bhi(hb.z)}, (v2f){blo(wb.z), bhi(wb.z)}, sacc);
      sacc = pk_fma((v2f){blo(hb.w), bhi(hb.w)}, (v2f){blo(wb.w), bhi(wb.w)}, sacc);
    }
    float pv = sacc.x + sacc.y;
    pv += __shfl_xor(pv, 16, 64);     // combine halves within 32-lane sample group
    pv += plb[k];
    __sincosf(pv * 0.5f, &sv, &cv);
  }

  // ---- 4-qubit circuit: 16-lane groups; groups 1,3 duplicate groups 0,2 ----
  {
    const int l = k;                  // amp index within group
    const int gb = lane & 48;         // group base for param broadcasts
    float re = (l == 0) ? 1.0f : 0.0f;
    float im = 0.0f;
    #pragma unroll
    for (int qi = 0; qi < 4; qi++) {
      const int beta = 3 - qi;
      const int m = 1 << beta;        // <16: shfl_xor stays in group
      const int b = (l >> beta) & 1;
      float c = __shfl(cv, gb + 4 * qi, 64), s = __shfl(sv, gb + 4 * qi, 64);
      float pr_ = __shfl_xor(re, m, 64), pi_ = __shfl_xor(im, m, 64);
      float sg = b ? s : -s;
      re = fmaf(c, re, sg * pr_);
      im = fmaf(c, im, sg * pi_);
      c = __shfl(cv, gb + 4 * qi + 1, 64); s = __shfl(sv, gb + 4 * qi + 1, 64);
      float sz = b ? s : -s;
      float nr = c * re - sz * im;
      float ni = c * im + sz * re;
      re = nr; im = ni;
      c = __shfl(cv, gb + 4 * qi + 2, 64); s = __shfl(sv, gb + 4 * qi + 2, 64);
      pr_ = __shfl_xor(re, m, 64); pi_ = __shfl_xor(im, m, 64);
      nr = fmaf(c, re, s * pi_);
      ni = fmaf(c, im, -s * pr_);
      re = nr; im = ni;
      const int tm = 1 << (3 - ((qi + 1) & 3));   // <16: in-group
      float fr = __shfl_xor(re, tm, 64), fi = __shfl_xor(im, tm, 64);
      if (b) { re = fr; im = fi; }
    }
    float pr2 = re * re + im * im;
    float z0 = ((l >> 3) & 1) ? -pr2 : pr2;
    float z1 = ((l >> 2) & 1) ? -pr2 : pr2;
    float z2 = ((l >> 1) & 1) ? -pr2 : pr2;
    float z3 = (l & 1) ? -pr2 : pr2;
    #pragma unroll
    for (int off = 8; off >= 1; off >>= 1) {      // in-group reductions
      z0 += __shfl_xor(z0, off, 64);
      z1 += __shfl_xor(z1, off, 64);
      z2 += __shfl_xor(z2, off, 64);
      z3 += __shfl_xor(z3, off, 64);
    }
    float as0 = 0.f, as1 = 0.f, as2 = 0.f, as3 = 0.f;
    float aq0 = 0.f, aq1 = 0.f, aq2 = 0.f, aq3 = 0.f;
    if (l == 0 && (lane & 16) == 0) {  // lanes 0,32: one sample each (no dups)
      float o0 = fmaf(rw[0],  z0, fmaf(rw[1],  z1, fmaf(rw[2],  z2, fmaf(rw[3],  z3, rb[0]))));
      float o1 = fmaf(rw[4],  z0, fmaf(rw[5],  z1, fmaf(rw[6],  z2, fmaf(rw[7],  z3, rb[1]))));
      float o2 = fmaf(rw[8],  z0, fmaf(rw[9],  z1, fmaf(rw[10], z2, fmaf(rw[11], z3, rb[2]))));
      float o3 = fmaf(rw[12], z0, fmaf(rw[13], z1, fmaf(rw[14], z2, fmaf(rw[15], z3, rb[3]))));
      *(float4*)(pre + (size_t)(base + s2) * 4) = make_float4(o0, o1, o2, o3);
      as0 = o0; aq0 = o0 * o0;
      as1 = o1; aq1 = o1 * o1;
      as2 = o2; aq2 = o2 * o2;
      as3 = o3; aq3 = o3 * o3;
    }
    as0 += __shfl_down(as0, 32, 64); aq0 += __shfl_down(aq0, 32, 64);
    as1 += __shfl_down(as1, 32, 64); aq1 += __shfl_down(aq1, 32, 64);
    as2 += __shfl_down(as2, 32, 64); aq2 += __shfl_down(aq2, 32, 64);
    as3 += __shfl_down(as3, 32, 64); aq3 += __shfl_down(aq3, 32, 64);
    if (lane == 0) {
      s_red[w][0] = as0; s_red[w][4] = aq0;
      s_red[w][1] = as1; s_red[w][5] = aq1;
      s_red[w][2] = as2; s_red[w][6] = aq2;
      s_red[w][3] = as3; s_red[w][7] = aq3;
    }
  }
  __syncthreads();
  if (tid < 8) {
    float v = s_red[0][tid] + s_red[1][tid] + s_red[2][tid] + s_red[3][tid];
    atomicAdd(&stats[tid], v);
  }
}

__global__ __launch_bounds__(256) void qnat_bn(
    float* __restrict__ pre,
    const float* __restrict__ stats,
    const float* __restrict__ bnw,
    const float* __restrict__ bnb)
{
  int idx = blockIdx.x * 256 + threadIdx.x;
  int c = idx & 3;
  float mean = stats[c] * (1.0f / BATCH);
  float ex2 = stats[4 + c] * (1.0f / BATCH);
  float var = ex2 - mean * mean;
  float inv = rsqrtf(var + 1e-5f);
  pre[idx] = (pre[idx] - mean) * inv * bnw[c] + bnb[c];
}

extern "C" void kernel_launch(void* const* d_in, const int* in_sizes, int n_in,
                              void* d_out, int out_size, void* d_ws, size_t ws_size,
                              hipStream_t stream) {
  const float* x   = (const float*)d_in[0];
  const float* w1  = (const float*)d_in[1];
  const float* b1  = (const float*)d_in[2];
  const float* w2  = (const float*)d_in[3];
  const float* b2  = (const float*)d_in[4];
  const float* plw = (const float*)d_in[5];
  const float* plb = (const float*)d_in[6];
  const float* rw  = (const float*)d_in[7];
  const float* rb  = (const float*)d_in[8];
  const float* bnw = (const float*)d_in[9];
  const float* bnb = (const float*)d_in[10];

  float* out   = (float*)d_out;
  float* stats = (float*)d_ws;

  hipMemsetAsync(stats, 0, 8 * sizeof(float), stream);
  qnat_fused<<<BATCH / 8, 256, 0, stream>>>(x, w1, b1, w2, b2, plw, plb, rw, rb, out, stats);
  qnat_bn<<<(BATCH * 4) / 256, 256, 0, stream>>>(out, stats, bnw, bnb);
}

// Round 2
// 145.549 us; speedup vs baseline: 1.5395x; 1.5395x over previous
//
#include <hip/hip_runtime.h>
#include <math.h>

#define BATCH 16384

typedef float v2f __attribute__((ext_vector_type(2)));
typedef unsigned short u16;

__device__ __forceinline__ v2f pk_fma(v2f a, v2f b, v2f c) {
  return __builtin_elementwise_fma(a, b, c);   // -> v_pk_fma_f32
}
__device__ __forceinline__ v2f pk_max(v2f a, v2f b) {
  return __builtin_elementwise_max(a, b);      // -> v_pk_max_f32
}

// RNE-pack two floats into a bf16 pair (lo -> low16, hi -> high16), scalar path
__device__ __forceinline__ unsigned bf2(float lo, float hi) {
  unsigned a = __float_as_uint(lo);
  unsigned b = __float_as_uint(hi);
  a = (a + 0x7fffu + ((a >> 16) & 1u)) >> 16;
  b = (b + 0x7fffu + ((b >> 16) & 1u)) & 0xffff0000u;
  return a | b;
}

// single-inst RNE pack: dst.lo16 = bf16(lo), dst.hi16 = bf16(hi)
__device__ __forceinline__ unsigned cvtpk(float lo, float hi) {
  unsigned r;
  asm("v_cvt_pk_bf16_f32 %0, %1, %2" : "=v"(r) : "v"(lo), "v"(hi));
  return r;
}
__device__ __forceinline__ float blo(unsigned u) { return __uint_as_float(u << 16); }
__device__ __forceinline__ float bhi(unsigned u) { return __uint_as_float(u & 0xffff0000u); }

// v13: v12 occupancy plan, spill-free. v12 post-mortem: __launch_bounds__(256,8)
// drove the allocator to a 32-VGPR budget vs ~60-reg demand -> 300MB scratch
// traffic (WRITE_SIZE 146MB), dur 133us. Occupancy mechanism itself confirmed
// (22%->73%). v13: NO min-waves hint; instead conv1 re-decomposed into
// 2-pooled-col units (98 pos/sample, 2 exec-masked sub-iters) so per-lane live
// set is win[4][6]+4 v2f acc (~45-50 regs). Goal: natural allocation <=64 ->
// 8 waves/SIMD with the 19.4KB LDS. If it lands 65+, dur is neutral (~47us
// fused), no cliff.
__global__ __launch_bounds__(256) void qnat_fused(
    const float* __restrict__ x,    // (B,1,28,28)
    const float* __restrict__ w1,   // (4,1,3,3)  uniform -> s_load
    const float* __restrict__ b1,   // (4,)
    const float* __restrict__ w2,   // (4,4,3,3)  uniform -> s_load
    const float* __restrict__ b2,   // (4,)
    const float* __restrict__ plw,  // (16,196)
    const float* __restrict__ plb,  // (16,)
    const float* __restrict__ rw,   // (4,4)
    const float* __restrict__ rb,   // (4,)
    float* __restrict__ pre,        // (B,4) pre-BN output (in d_out)
    float* __restrict__ stats)      // [8] {sum_c, sumsq_c}
{
  // per-wave h1 (bf16): 4 ch x (16 rows x 18 cols), ch stride 288 shorts.
  // data col c at stored c+1; rows 0,15 / cols 0,15+ are persistent zero pads.
  __shared__ __align__(16) u16 h1s[4][4 * 288];
  // per-wave h2 (bf16): 2 sample slots x 208 shorts (196 data + 12 zero pad)
  __shared__ __align__(16) u16 h2s[4][2][208];
  // block-shared transposed bf16 plw: row t (f=8t..8t+7) x 16 k-cols; row 25 = 0
  __shared__ __align__(16) uint4 plw_tb[26 * 16];
  __shared__ float s_red[4][8];

  const int tid = threadIdx.x;
  const int w = tid >> 6;
  const int lane = tid & 63;
  const int base = (blockIdx.x * 4 + w) * 2;    // first of 2 samples

  // ---- stage plw -> plw_tb (bf16, transposed), once per block ----
  #pragma unroll
  for (int j = 0; j < 2; j++) {
    int s = tid + 256 * j;
    if (s < 416) {
      int tp = s >> 4;                // 0..25
      int k2 = s & 15;
      uint4 v = make_uint4(0u, 0u, 0u, 0u);
      if (tp < 25) {
        const float4* pr = (const float4*)(plw + k2 * 196);
        float4 a = pr[2 * tp];
        float4 b = (tp < 24) ? pr[2 * tp + 1] : make_float4(0.f, 0.f, 0.f, 0.f);
        v = make_uint4(bf2(a.x, a.y), bf2(a.z, a.w),
                       bf2(b.x, b.y), bf2(b.z, b.w));
      }
      plw_tb[s] = v;
    }
  }

  // ---- zero h1s fully + h2 tail pads (wave-private) ----
  {
    uint4 z4 = make_uint4(0u, 0u, 0u, 0u);
    uint4* hz = (uint4*)&h1s[w][0];             // 2304B = 144 uint4
    #pragma unroll
    for (int t = 0; t < 3; t++) {
      int p = t * 64 + lane;
      if (p < 144) hz[p] = z4;
    }
    if (lane < 4) {                              // shorts 192..207 of each slot
      uint4* hp4 = (uint4*)&h2s[w][lane >> 1][0];
      hp4[24 + (lane & 1)] = z4;
    }
  }
  __syncthreads();   // plw_tb visible

  // ================= stage 1: conv both layers for 2 samples =================
  for (int it = 0; it < 2; ++it) {
    const float* xb = x + (size_t)(base + it) * 784;

    // ---- conv1 + relu + pool -> h1s (bf16); 2-pooled-col units ----
    // pos in [0,98): i = pos/7 pooled row, h = pos%7 col pair (pooled 2h,2h+1)
    #pragma unroll
    for (int sub = 0; sub < 2; ++sub) {
      int pos = sub * 64 + lane;
      if (pos < 98) {
        int i = (pos * 9363) >> 16;   // pos/7 for pos<=97
        int h = pos - 7 * i;
        // window: rows 2i-1..2i+2, input cols 4h-1..4h+4
        float win[4][6];
        #pragma unroll
        for (int r = 0; r < 4; r++) {
          int row = 2 * i - 1 + r;
          if (0 <= row && row < 28) {
            const float* rp = xb + row * 28 + 4 * h;
            float4 a = *(const float4*)rp;
            win[r][0] = (h > 0) ? rp[-1] : 0.0f;
            win[r][1] = a.x; win[r][2] = a.y; win[r][3] = a.z; win[r][4] = a.w;
            win[r][5] = (h < 6) ? rp[4] : 0.0f;
          } else {
            #pragma unroll
            for (int kk = 0; kk < 6; kk++) win[r][kk] = 0.0f;
          }
        }
        u16* hb = &h1s[w][18 * (i + 1) + 1 + 2 * h];
        #pragma unroll
        for (int c = 0; c < 4; c++) {
          const float* wc = w1 + c * 9;
          const v2f bias2 = (v2f){b1[c], b1[c]};
          v2f a0[2], a1[2];
          a0[0] = bias2; a0[1] = bias2;
          a1[0] = bias2; a1[1] = bias2;
          #pragma unroll
          for (int dy = 0; dy < 3; dy++)
            #pragma unroll
            for (int dx = 0; dx < 3; dx++) {
              const float wv = wc[dy * 3 + dx];
              const v2f wvv = (v2f){wv, wv};
              #pragma unroll
              for (int jj = 0; jj < 2; jj++) {
                a0[jj] = pk_fma((v2f){win[dy][2 * jj + dx],     win[dy][2 * jj + dx + 1]},     wvv, a0[jj]);
                a1[jj] = pk_fma((v2f){win[dy + 1][2 * jj + dx], win[dy + 1][2 * jj + dx + 1]}, wvv, a1[jj]);
              }
            }
          v2f mm0 = pk_max(a0[0], a1[0]);
          v2f mm1 = pk_max(a0[1], a1[1]);
          float m0 = fmaxf(fmaxf(mm0.x, mm0.y), 0.0f);
          float m1 = fmaxf(fmaxf(mm1.x, mm1.y), 0.0f);
          unsigned u01 = cvtpk(m0, m1);
          u16* p = hb + 288 * c;
          p[0] = (u16)u01;
          p[1] = (u16)(u01 >> 16);
        }
      }
    }
    // h1s wave-private: no barrier (compiler orders ds ops via lgkmcnt).

    // ---- conv2 + relu + pool -> h2s[w][it] (bf16) ----
    {
      const int jq = lane & 7;
      const int i2 = lane >> 3;
      if (i2 < 7 && jq < 7) {
        v2f acc[4][2];
        #pragma unroll
        for (int co = 0; co < 4; co++) {
          const v2f bb = (v2f){b2[co], b2[co]};
          acc[co][0] = bb; acc[co][1] = bb;
        }
        #pragma unroll
        for (int ci = 0; ci < 4; ci++) {
          const u16* rp = &h1s[w][288 * ci + 36 * i2 + 2 * jq];
          v2f Q[4][3];
          #pragma unroll
          for (int r = 0; r < 4; r++) {
            unsigned u0 = *(const unsigned*)(rp + 18 * r);      // cols 2jq,2jq+1
            unsigned u1 = *(const unsigned*)(rp + 18 * r + 2);  // cols 2jq+2,2jq+3
            float f0 = blo(u0), f1 = bhi(u0), f2 = blo(u1), f3 = bhi(u1);
            Q[r][0] = (v2f){f0, f1};
            Q[r][1] = (v2f){f1, f2};
            Q[r][2] = (v2f){f2, f3};
          }
          #pragma unroll
          for (int co = 0; co < 4; co++) {
            const float* wp = w2 + (co * 4 + ci) * 9;
            #pragma unroll
            for (int dy = 0; dy < 3; dy++)
              #pragma unroll
              for (int dx = 0; dx < 3; dx++) {
                const float wv = wp[dy * 3 + dx];
                const v2f wvv = (v2f){wv, wv};
                acc[co][0] = pk_fma(Q[dy][dx],     wvv, acc[co][0]);
                acc[co][1] = pk_fma(Q[dy + 1][dx], wvv, acc[co][1]);
              }
          }
        }
        float mo[4];
        #pragma unroll
        for (int co = 0; co < 4; co++) {
          v2f mm = pk_max(acc[co][0], acc[co][1]);
          mo[co] = fmaxf(fmaxf(mm.x, mm.y), 0.0f);
        }
        unsigned u01 = cvtpk(mo[0], mo[1]);
        unsigned u23 = cvtpk(mo[2], mo[3]);
        u16* hp = &h2s[w][it][7 * i2 + jq];
        hp[0]   = (u16)u01;
        hp[49]  = (u16)(u01 >> 16);
        hp[98]  = (u16)u23;
        hp[147] = (u16)(u23 >> 16);
      }
    }
    // h2s wave-private: no barrier.
  }

  // ============ stage 2: linear + circuit, 2 samples, all 64 lanes ============
  const int s2 = lane >> 5;           // sample slot 0..1
  const int half = (lane >> 4) & 1;   // dot-product half
  const int k = lane & 15;            // param index / amp index

  // ---- linear: 196-dot split across two 16-lane halves; LDS-only operands ----
  float cv, sv;
  {
    const uint4* hb4 = (const uint4*)&h2s[w][s2][0];   // 26 uint4, broadcast
    const uint4* wb4 = &plw_tb[k];                     // row stride 16 uint4s
    v2f sacc = (v2f){0.0f, 0.0f};
    #pragma unroll
    for (int tt = 0; tt < 13; tt++) {
      int t = 2 * tt + half;                           // t=25 reads zero pad
      uint4 hb = hb4[t];
      uint4 wb = wb4[16 * t];
      sacc = pk_fma((v2f){blo(hb.x), bhi(hb.x)}, (v2f){blo(wb.x), bhi(wb.x)}, sacc);
      sacc = pk_fma((v2f){blo(hb.y), bhi(hb.y)}, (v2f){blo(wb.y), bhi(wb.y)}, sacc);
      sacc = pk_fma((v2f){blo(hb.z), bhi(hb.z)}, (v2f){blo(wb.z), bhi(wb.z)}, sacc);
      sacc = pk_fma((v2f){blo(hb.w), bhi(hb.w)}, (v2f){blo(wb.w), bhi(wb.w)}, sacc);
    }
    float pv = sacc.x + sacc.y;
    pv += __shfl_xor(pv, 16, 64);     // combine halves within 32-lane sample group
    pv += plb[k];
    __sincosf(pv * 0.5f, &sv, &cv);
  }

  // ---- 4-qubit circuit: 16-lane groups; groups 1,3 duplicate groups 0,2 ----
  {
    const int l = k;                  // amp index within group
    const int gb = lane & 48;         // group base for param broadcasts
    float re = (l == 0) ? 1.0f : 0.0f;
    float im = 0.0f;
    #pragma unroll
    for (int qi = 0; qi < 4; qi++) {
      const int beta = 3 - qi;
      const int m = 1 << beta;        // <16: shfl_xor stays in group
      const int b = (l >> beta) & 1;
      float c = __shfl(cv, gb + 4 * qi, 64), s = __shfl(sv, gb + 4 * qi, 64);
      float pr_ = __shfl_xor(re, m, 64), pi_ = __shfl_xor(im, m, 64);
      float sg = b ? s : -s;
      re = fmaf(c, re, sg * pr_);
      im = fmaf(c, im, sg * pi_);
      c = __shfl(cv, gb + 4 * qi + 1, 64); s = __shfl(sv, gb + 4 * qi + 1, 64);
      float sz = b ? s : -s;
      float nr = c * re - sz * im;
      float ni = c * im + sz * re;
      re = nr; im = ni;
      c = __shfl(cv, gb + 4 * qi + 2, 64); s = __shfl(sv, gb + 4 * qi + 2, 64);
      pr_ = __shfl_xor(re, m, 64); pi_ = __shfl_xor(im, m, 64);
      nr = fmaf(c, re, s * pi_);
      ni = fmaf(c, im, -s * pr_);
      re = nr; im = ni;
      const int tm = 1 << (3 - ((qi + 1) & 3));   // <16: in-group
      float fr = __shfl_xor(re, tm, 64), fi = __shfl_xor(im, tm, 64);
      if (b) { re = fr; im = fi; }
    }
    float pr2 = re * re + im * im;
    float z0 = ((l >> 3) & 1) ? -pr2 : pr2;
    float z1 = ((l >> 2) & 1) ? -pr2 : pr2;
    float z2 = ((l >> 1) & 1) ? -pr2 : pr2;
    float z3 = (l & 1) ? -pr2 : pr2;
    #pragma unroll
    for (int off = 8; off >= 1; off >>= 1) {      // in-group reductions
      z0 += __shfl_xor(z0, off, 64);
      z1 += __shfl_xor(z1, off, 64);
      z2 += __shfl_xor(z2, off, 64);
      z3 += __shfl_xor(z3, off, 64);
    }
    float as0 = 0.f, as1 = 0.f, as2 = 0.f, as3 = 0.f;
    float aq0 = 0.f, aq1 = 0.f, aq2 = 0.f, aq3 = 0.f;
    if (l == 0 && (lane & 16) == 0) {  // lanes 0,32: one sample each (no dups)
      float o0 = fmaf(rw[0],  z0, fmaf(rw[1],  z1, fmaf(rw[2],  z2, fmaf(rw[3],  z3, rb[0]))));
      float o1 = fmaf(rw[4],  z0, fmaf(rw[5],  z1, fmaf(rw[6],  z2, fmaf(rw[7],  z3, rb[1]))));
      float o2 = fmaf(rw[8],  z0, fmaf(rw[9],  z1, fmaf(rw[10], z2, fmaf(rw[11], z3, rb[2]))));
      float o3 = fmaf(rw[12], z0, fmaf(rw[13], z1, fmaf(rw[14], z2, fmaf(rw[15], z3, rb[3]))));
      *(float4*)(pre + (size_t)(base + s2) * 4) = make_float4(o0, o1, o2, o3);
      as0 = o0; aq0 = o0 * o0;
      as1 = o1; aq1 = o1 * o1;
      as2 = o2; aq2 = o2 * o2;
      as3 = o3; aq3 = o3 * o3;
    }
    as0 += __shfl_down(as0, 32, 64); aq0 += __shfl_down(aq0, 32, 64);
    as1 += __shfl_down(as1, 32, 64); aq1 += __shfl_down(aq1, 32, 64);
    as2 += __shfl_down(as2, 32, 64); aq2 += __shfl_down(aq2, 32, 64);
    as3 += __shfl_down(as3, 32, 64); aq3 += __shfl_down(aq3, 32, 64);
    if (lane == 0) {
      s_red[w][0] = as0; s_red[w][4] = aq0;
      s_red[w][1] = as1; s_red[w][5] = aq1;
      s_red[w][2] = as2; s_red[w][6] = aq2;
      s_red[w][3] = as3; s_red[w][7] = aq3;
    }
  }
  __syncthreads();
  if (tid < 8) {
    float v = s_red[0][tid] + s_red[1][tid] + s_red[2][tid] + s_red[3][tid];
    atomicAdd(&stats[tid], v);
  }
}

__global__ __launch_bounds__(256) void qnat_bn(
    float* __restrict__ pre,
    const float* __restrict__ stats,
    const float* __restrict__ bnw,
    const float* __restrict__ bnb)
{
  int idx = blockIdx.x * 256 + threadIdx.x;
  int c = idx & 3;
  float mean = stats[c] * (1.0f / BATCH);
  float ex2 = stats[4 + c] * (1.0f / BATCH);
  float var = ex2 - mean * mean;
  float inv = rsqrtf(var + 1e-5f);
  pre[idx] = (pre[idx] - mean) * inv * bnw[c] + bnb[c];
}

extern "C" void kernel_launch(void* const* d_in, const int* in_sizes, int n_in,
                              void* d_out, int out_size, void* d_ws, size_t ws_size,
                              hipStream_t stream) {
  const float* x   = (const float*)d_in[0];
  const float* w1  = (const float*)d_in[1];
  const float* b1  = (const float*)d_in[2];
  const float* w2  = (const float*)d_in[3];
  const float* b2  = (const float*)d_in[4];
  const float* plw = (const float*)d_in[5];
  const float* plb = (const float*)d_in[6];
  const float* rw  = (const float*)d_in[7];
  const float* rb  = (const float*)d_in[8];
  const float* bnw = (const float*)d_in[9];
  const float* bnb = (const float*)d_in[10];

  float* out   = (float*)d_out;
  float* stats = (float*)d_ws;

  hipMemsetAsync(stats, 0, 8 * sizeof(float), stream);
  qnat_fused<<<BATCH / 8, 256, 0, stream>>>(x, w1, b1, w2, b2, plw, plb, rw, rb, out, stats);
  qnat_bn<<<(BATCH * 4) / 256, 256, 0, stream>>>(out, stats, bnw, bnb);
}

// Round 3
// 133.239 us; speedup vs baseline: 1.6818x; 1.0924x over previous
//
#include <hip/hip_runtime.h>
#include <math.h>

#define BATCH 16384

typedef float v2f __attribute__((ext_vector_type(2)));

__device__ __forceinline__ v2f pk_fma(v2f a, v2f b, v2f c) {
  return __builtin_elementwise_fma(a, b, c);   // -> v_pk_fma_f32
}
__device__ __forceinline__ v2f pk_max(v2f a, v2f b) {
  return __builtin_elementwise_max(a, b);      // -> v_pk_max_f32
}

// RNE-pack two floats into a bf16 pair (lo -> low16, hi -> high16)
__device__ __forceinline__ unsigned bf2(float lo, float hi) {
  unsigned a = __float_as_uint(lo);
  unsigned b = __float_as_uint(hi);
  a = (a + 0x7fffu + ((a >> 16) & 1u)) >> 16;
  b = (b + 0x7fffu + ((b >> 16) & 1u)) & 0xffff0000u;
  return a | b;
}

// v14 = v8 (best measured: fused 46.5us, total 134.2us) with ONE change:
// the 4-sample it-loop is forced rolled (#pragma unroll 1). v8's full unroll
// gives ~5K instructions (~40KB text) > 32KB L1I -> continuous I-fetch misses,
// which explains the occupancy-insensitive VALUBusy~50% cap (v12/v13 showed
// raising occupancy 22->73% never moved VALUBusy). Rolled body ~1.2KB stays
// I-cache resident. Occupancy path is dead: v13 (2 samp/wave, 19KB LDS,
// 56 VGPR) regressed to 61us fused -- extra stage-2 amortization + masked
// conv1 lanes cost more than TLP gains. Keep 4 samples/wave, fp32 LDS,
// full prefetch, VGPR=72 tolerated.
__global__ __launch_bounds__(256) void qnat_fused(
    const float* __restrict__ x,    // (B,1,28,28)
    const float* __restrict__ w1,   // (4,1,3,3)  uniform -> s_load
    const float* __restrict__ b1,   // (4,)
    const float* __restrict__ w2,   // (4,4,3,3)  uniform -> s_load
    const float* __restrict__ b2,   // (4,)
    const float* __restrict__ plw,  // (16,196)
    const float* __restrict__ plb,  // (16,)
    const float* __restrict__ rw,   // (4,4)
    const float* __restrict__ rb,   // (4,)
    float* __restrict__ pre,        // (B,4) pre-BN output (in d_out)
    float* __restrict__ stats)      // [8] {sum_c, sumsq_c}
{
  // per-wave h1p: 4 ch x (16 rows x 18 cols) fp32, ch stride 288; data col c
  // at stored c+1 (rows 0,15 / cols 0,15 zero pads persist across iterations).
  __shared__ __align__(16) float h1p[4][4 * 288 + 16];
  // per-wave h2: 4 sample slots x 200 fp32 (196 data + 4 zero pad)
  __shared__ __align__(16) float h2[4][4][200];
  // block-shared transposed bf16 plw: row t (f=8t..8t+7) x 16 k-columns
  __shared__ __align__(16) uint4 plw_tb[25 * 16];
  __shared__ float s_red[4][8];

  const int tid = threadIdx.x;
  const int w = tid >> 6;
  const int lane = tid & 63;
  const int base = (blockIdx.x * 4 + w) * 4;    // first of 4 samples

  // ---- stage plw -> plw_tb (bf16, transposed), once per block ----
  #pragma unroll
  for (int j = 0; j < 2; j++) {
    int s = tid + 256 * j;
    if (s < 400) {
      int tp = s >> 4;                // 0..24
      int k = s & 15;
      const float4* pr = (const float4*)(plw + k * 196);
      float4 a = pr[2 * tp];
      float4 b = (tp < 24) ? pr[2 * tp + 1] : make_float4(0.f, 0.f, 0.f, 0.f);
      plw_tb[s] = make_uint4(bf2(a.x, a.y), bf2(a.z, a.w),
                             bf2(b.x, b.y), bf2(b.z, b.w));
    }
  }

  // ---- zero h1p pads + h2 pads (wave-private) ----
  {
    float4 z4 = make_float4(0.f, 0.f, 0.f, 0.f);
    float4* hz = (float4*)&h1p[w][0];
    #pragma unroll
    for (int t = 0; t < 5; t++) {
      int p = t * 64 + lane;
      if (p < 292) hz[p] = z4;
    }
    if (lane < 16) h2[w][lane >> 2][196 + (lane & 3)] = 0.0f;
  }
  __syncthreads();   // plw_tb visible

  const int i = lane >> 2;            // conv1: pooled row 0..13
  const int q = lane & 3;             // conv1: col quad
  const bool c1act = lane < 56;

  // prefetch buffers for conv1 windows (cols 8q-1 .. 8q+8 fully covered)
  float4 pfa[4], pfb[4];
  float pe0[4], pe1[4];
  #pragma unroll
  for (int r = 0; r < 4; r++) {
    pfa[r] = make_float4(0,0,0,0); pfb[r] = make_float4(0,0,0,0);
    pe0[r] = 0.0f; pe1[r] = 0.0f;
  }

  if (c1act) {
    const float* xb = x + (size_t)base * 784;
    #pragma unroll
    for (int r = 0; r < 4; r++) {
      int row = 2 * i - 1 + r;
      if (0 <= row && row < 28) {
        const float* rp = xb + row * 28;
        pfa[r] = *(const float4*)(rp + 8 * q);
        if (q > 0) pe0[r] = rp[8 * q - 1];
        if (q < 3) {
          pfb[r] = *(const float4*)(rp + 8 * q + 4);
          pe1[r] = rp[8 * q + 8];
        }
      }
    }
  }

  // ================= stage 1: conv both layers for 4 samples =================
  #pragma unroll 1   // keep rolled: unrolled body (~40KB) thrashes the 32KB L1I
  for (int it = 0; it < 4; ++it) {
    // ---- conv1 + relu + pool ----
    if (c1act) {
      float win[4][10];               // win[r][k] <-> input col 8q-1+k
      #pragma unroll
      for (int r = 0; r < 4; r++) {
        win[r][0] = pe0[r];
        win[r][1] = pfa[r].x; win[r][2] = pfa[r].y;
        win[r][3] = pfa[r].z; win[r][4] = pfa[r].w;
        win[r][5] = pfb[r].x; win[r][6] = pfb[r].y;
        win[r][7] = pfb[r].z; win[r][8] = pfb[r].w;
        win[r][9] = pe1[r];
      }
      // prefetch next sample's rows while conv1 FMAs run
      if (it != 3) {
        const float* xn = x + (size_t)(base + it + 1) * 784;
        #pragma unroll
        for (int r = 0; r < 4; r++) {
          int row = 2 * i - 1 + r;
          pfa[r] = make_float4(0,0,0,0);
          pfb[r] = make_float4(0,0,0,0);
          pe0[r] = 0.0f; pe1[r] = 0.0f;
          if (0 <= row && row < 28) {
            const float* rp = xn + row * 28;
            pfa[r] = *(const float4*)(rp + 8 * q);
            if (q > 0) pe0[r] = rp[8 * q - 1];
            if (q < 3) {
              pfb[r] = *(const float4*)(rp + 8 * q + 4);
              pe1[r] = rp[8 * q + 8];
            }
          }
        }
      }
      v2f P[4][9];
      #pragma unroll
      for (int r = 0; r < 4; r++)
        #pragma unroll
        for (int k = 0; k < 9; k++) P[r][k] = (v2f){win[r][k], win[r][k + 1]};

      float* hb = &h1p[w][18 * (i + 1) + 1 + 4 * q];
      #pragma unroll
      for (int c = 0; c < 4; c++) {
        const float* wc = w1 + c * 9;
        const v2f bias2 = (v2f){b1[c], b1[c]};
        v2f a0[4], a1[4];
        #pragma unroll
        for (int jj = 0; jj < 4; jj++) { a0[jj] = bias2; a1[jj] = bias2; }
        #pragma unroll
        for (int dy = 0; dy < 3; dy++)
          #pragma unroll
          for (int dx = 0; dx < 3; dx++) {
            const float wv = wc[dy * 3 + dx];
            const v2f wvv = (v2f){wv, wv};
            #pragma unroll
            for (int jj = 0; jj < 4; jj++) {
              a0[jj] = pk_fma(P[dy][2 * jj + dx],     wvv, a0[jj]);
              a1[jj] = pk_fma(P[dy + 1][2 * jj + dx], wvv, a1[jj]);
            }
          }
        float m[4];
        #pragma unroll
        for (int jj = 0; jj < 4; jj++) {
          v2f mm = pk_max(a0[jj], a1[jj]);
          m[jj] = fmaxf(fmaxf(mm.x, mm.y), 0.0f);
        }
        float* p = hb + 288 * c;
        if (q < 3) {
          p[0] = m[0];
          *(float2*)(p + 1) = make_float2(m[1], m[2]);
          p[3] = m[3];
        } else {
          p[0] = m[0];
          p[1] = m[1];
        }
      }
    }
    // h1p wave-private: no barrier.

    // ---- conv2 + relu + pool -> h2[w][it] ----
    {
      const int jq = lane & 7;
      const int i2 = lane >> 3;
      if (i2 < 7 && jq < 7) {
        v2f acc[4][2];
        #pragma unroll
        for (int co = 0; co < 4; co++) {
          const v2f bb = (v2f){b2[co], b2[co]};
          acc[co][0] = bb; acc[co][1] = bb;
        }
        #pragma unroll
        for (int ci = 0; ci < 4; ci++) {
          const float* rp = &h1p[w][288 * ci + 36 * i2 + 2 * jq];
          v2f Q[4][3];
          #pragma unroll
          for (int r = 0; r < 4; r++) {
            v2f a = *(const v2f*)(rp + 18 * r);
            v2f b = *(const v2f*)(rp + 18 * r + 2);
            Q[r][0] = a;
            Q[r][1] = (v2f){a.y, b.x};
            Q[r][2] = b;
          }
          #pragma unroll
          for (int co = 0; co < 4; co++) {
            const float* wp = w2 + (co * 4 + ci) * 9;
            #pragma unroll
            for (int dy = 0; dy < 3; dy++)
              #pragma unroll
              for (int dx = 0; dx < 3; dx++) {
                const float wv = wp[dy * 3 + dx];
                const v2f wvv = (v2f){wv, wv};
                acc[co][0] = pk_fma(Q[dy][dx],     wvv, acc[co][0]);
                acc[co][1] = pk_fma(Q[dy + 1][dx], wvv, acc[co][1]);
              }
          }
        }
        #pragma unroll
        for (int co = 0; co < 4; co++) {
          v2f mm = pk_max(acc[co][0], acc[co][1]);
          h2[w][it][49 * co + 7 * i2 + jq] = fmaxf(fmaxf(mm.x, mm.y), 0.0f);
        }
      }
    }
    // h2 wave-private: no barrier.
  }

  // ============ stage 2: linear + circuit for all 4 samples batched ============
  const int s2 = lane >> 4;           // sample slot 0..3
  const int k = lane & 15;            // param index / amp index

  // ---- linear: one full 196-dot per lane; LDS-only operands ----
  float cv, sv;
  {
    const float4* hv4 = (const float4*)&h2[w][s2][0];   // broadcast, conflict-free
    const uint4*  wb4 = &plw_tb[k];                     // row stride 16 uint4s
    v2f sacc = (v2f){0.0f, 0.0f};
    #pragma unroll
    for (int t = 0; t < 25; t++) {
      float4 h0 = hv4[2 * t];
      float4 h1 = hv4[2 * t + 1];
      uint4 wb = wb4[16 * t];
      v2f w01 = (v2f){__uint_as_float(wb.x << 16), __uint_as_float(wb.x & 0xffff0000u)};
      v2f w23 = (v2f){__uint_as_float(wb.y << 16), __uint_as_float(wb.y & 0xffff0000u)};
      v2f w45 = (v2f){__uint_as_float(wb.z << 16), __uint_as_float(wb.z & 0xffff0000u)};
      v2f w67 = (v2f){__uint_as_float(wb.w << 16), __uint_as_float(wb.w & 0xffff0000u)};
      sacc = pk_fma((v2f){h0.x, h0.y}, w01, sacc);
      sacc = pk_fma((v2f){h0.z, h0.w}, w23, sacc);
      sacc = pk_fma((v2f){h1.x, h1.y}, w45, sacc);
      sacc = pk_fma((v2f){h1.z, h1.w}, w67, sacc);
    }
    float pv = sacc.x + sacc.y + plb[k];
    __sincosf(pv * 0.5f, &sv, &cv);
  }

  // ---- 4-qubit circuit: 4 samples in parallel on 16-lane groups ----
  {
    const int l = k;                  // amp index within group
    const int gb = lane & 48;         // group base for param broadcasts
    float re = (l == 0) ? 1.0f : 0.0f;
    float im = 0.0f;
    #pragma unroll
    for (int qi = 0; qi < 4; qi++) {
      const int beta = 3 - qi;
      const int m = 1 << beta;        // <16: shfl_xor stays in group
      const int b = (l >> beta) & 1;
      float c = __shfl(cv, gb + 4 * qi, 64), s = __shfl(sv, gb + 4 * qi, 64);
      float pr_ = __shfl_xor(re, m, 64), pi_ = __shfl_xor(im, m, 64);
      float sg = b ? s : -s;
      re = fmaf(c, re, sg * pr_);
      im = fmaf(c, im, sg * pi_);
      c = __shfl(cv, gb + 4 * qi + 1, 64); s = __shfl(sv, gb + 4 * qi + 1, 64);
      float sz = b ? s : -s;
      float nr = c * re - sz * im;
      float ni = c * im + sz * re;
      re = nr; im = ni;
      c = __shfl(cv, gb + 4 * qi + 2, 64); s = __shfl(sv, gb + 4 * qi + 2, 64);
      pr_ = __shfl_xor(re, m, 64); pi_ = __shfl_xor(im, m, 64);
      nr = fmaf(c, re, s * pi_);
      ni = fmaf(c, im, -s * pr_);
      re = nr; im = ni;
      const int tm = 1 << (3 - ((qi + 1) & 3));   // <16: in-group
      float fr = __shfl_xor(re, tm, 64), fi = __shfl_xor(im, tm, 64);
      if (b) { re = fr; im = fi; }
    }
    float pr2 = re * re + im * im;
    float z0 = ((l >> 3) & 1) ? -pr2 : pr2;
    float z1 = ((l >> 2) & 1) ? -pr2 : pr2;
    float z2 = ((l >> 1) & 1) ? -pr2 : pr2;
    float z3 = (l & 1) ? -pr2 : pr2;
    #pragma unroll
    for (int off = 8; off >= 1; off >>= 1) {      // in-group reductions
      z0 += __shfl_xor(z0, off, 64);
      z1 += __shfl_xor(z1, off, 64);
      z2 += __shfl_xor(z2, off, 64);
      z3 += __shfl_xor(z3, off, 64);
    }
    float as0 = 0.f, as1 = 0.f, as2 = 0.f, as3 = 0.f;
    float aq0 = 0.f, aq1 = 0.f, aq2 = 0.f, aq3 = 0.f;
    if (l == 0) {                     // lanes 0,16,32,48: one sample each
      float o0 = fmaf(rw[0],  z0, fmaf(rw[1],  z1, fmaf(rw[2],  z2, fmaf(rw[3],  z3, rb[0]))));
      float o1 = fmaf(rw[4],  z0, fmaf(rw[5],  z1, fmaf(rw[6],  z2, fmaf(rw[7],  z3, rb[1]))));
      float o2 = fmaf(rw[8],  z0, fmaf(rw[9],  z1, fmaf(rw[10], z2, fmaf(rw[11], z3, rb[2]))));
      float o3 = fmaf(rw[12], z0, fmaf(rw[13], z1, fmaf(rw[14], z2, fmaf(rw[15], z3, rb[3]))));
      *(float4*)(pre + (size_t)(base + s2) * 4) = make_float4(o0, o1, o2, o3);
      as0 = o0; aq0 = o0 * o0;
      as1 = o1; aq1 = o1 * o1;
      as2 = o2; aq2 = o2 * o2;
      as3 = o3; aq3 = o3 * o3;
    }
    #pragma unroll
    for (int off = 32; off >= 16; off >>= 1) {
      as0 += __shfl_down(as0, off, 64); aq0 += __shfl_down(aq0, off, 64);
      as1 += __shfl_down(as1, off, 64); aq1 += __shfl_down(aq1, off, 64);
      as2 += __shfl_down(as2, off, 64); aq2 += __shfl_down(aq2, off, 64);
      as3 += __shfl_down(as3, off, 64); aq3 += __shfl_down(aq3, off, 64);
    }
    if (lane == 0) {
      s_red[w][0] = as0; s_red[w][4] = aq0;
      s_red[w][1] = as1; s_red[w][5] = aq1;
      s_red[w][2] = as2; s_red[w][6] = aq2;
      s_red[w][3] = as3; s_red[w][7] = aq3;
    }
  }
  __syncthreads();
  if (tid < 8) {
    float v = s_red[0][tid] + s_red[1][tid] + s_red[2][tid] + s_red[3][tid];
    atomicAdd(&stats[tid], v);
  }
}

__global__ __launch_bounds__(256) void qnat_bn(
    float* __restrict__ pre,
    const float* __restrict__ stats,
    const float* __restrict__ bnw,
    const float* __restrict__ bnb)
{
  int idx = blockIdx.x * 256 + threadIdx.x;
  int c = idx & 3;
  float mean = stats[c] * (1.0f / BATCH);
  float ex2 = stats[4 + c] * (1.0f / BATCH);
  float var = ex2 - mean * mean;
  float inv = rsqrtf(var + 1e-5f);
  pre[idx] = (pre[idx] - mean) * inv * bnw[c] + bnb[c];
}

extern "C" void kernel_launch(void* const* d_in, const int* in_sizes, int n_in,
                              void* d_out, int out_size, void* d_ws, size_t ws_size,
                              hipStream_t stream) {
  const float* x   = (const float*)d_in[0];
  const float* w1  = (const float*)d_in[1];
  const float* b1  = (const float*)d_in[2];
  const float* w2  = (const float*)d_in[3];
  const float* b2  = (const float*)d_in[4];
  const float* plw = (const float*)d_in[5];
  const float* plb = (const float*)d_in[6];
  const float* rw  = (const float*)d_in[7];
  const float* rb  = (const float*)d_in[8];
  const float* bnw = (const float*)d_in[9];
  const float* bnb = (const float*)d_in[10];

  float* out   = (float*)d_out;
  float* stats = (float*)d_ws;

  hipMemsetAsync(stats, 0, 8 * sizeof(float), stream);
  qnat_fused<<<BATCH / 16, 256, 0, stream>>>(x, w1, b1, w2, b2, plw, plb, rw, rb, out, stats);
  qnat_bn<<<(BATCH * 4) / 256, 256, 0, stream>>>(out, stats, bnw, bnb);
}

// Round 4
// 132.586 us; speedup vs baseline: 1.6900x; 1.0049x over previous
//
#include <hip/hip_runtime.h>
#include <math.h>

#define BATCH 16384

typedef float v2f __attribute__((ext_vector_type(2)));
typedef unsigned short u16;
typedef __attribute__((ext_vector_type(8))) short short8;
typedef __attribute__((ext_vector_type(4))) float f32x4;

__device__ __forceinline__ v2f pk_fma(v2f a, v2f b, v2f c) {
  return __builtin_elementwise_fma(a, b, c);   // -> v_pk_fma_f32
}
__device__ __forceinline__ v2f pk_max(v2f a, v2f b) {
  return __builtin_elementwise_max(a, b);      // -> v_pk_max_f32
}

// RNE-pack two floats into a bf16 pair (lo -> low16, hi -> high16)
__device__ __forceinline__ unsigned bf2(float lo, float hi) {
  unsigned a = __float_as_uint(lo);
  unsigned b = __float_as_uint(hi);
  a = (a + 0x7fffu + ((a >> 16) & 1u)) >> 16;
  b = (b + 0x7fffu + ((b >> 16) & 1u)) & 0xffff0000u;
  return a | b;
}

// single-inst RNE pack: dst.lo16 = bf16(lo), dst.hi16 = bf16(hi)
__device__ __forceinline__ unsigned cvtpk(float lo, float hi) {
  unsigned r;
  asm("v_cvt_pk_bf16_f32 %0, %1, %2" : "=v"(r) : "v"(lo), "v"(hi));
  return r;
}

// v15 = v14 + MFMA offload of the per-layer linear (196->16).
// Evidence: VALUBusy~50% invariant to occupancy (v8 16w/CU, v13 32w/CU) ->
// issue-bound on VALU/DS stream; MfmaUtil=0 -> matrix pipe idle and co-issues
// with VALU across waves (m114). The linear is a 16x196 @ 196x16 GEMM per
// block: h2 stored bf16 (block-shared, slot stride 232 shorts for 2-way-free
// fragment reads), plw_tb already in B-fragment layout, K padded to 224 ->
// 7x mfma_f32_16x16x32_bf16, all 4 waves redundant (pipe idle), each wave
// extracts its quadrant via 4 ds_bpermute + static selects.
// Replaces ~300 VALU + 75 ds_read_b128 per wave.
__global__ __launch_bounds__(256) void qnat_fused(
    const float* __restrict__ x,    // (B,1,28,28)
    const float* __restrict__ w1,   // (4,1,3,3)  uniform -> s_load
    const float* __restrict__ b1,   // (4,)
    const float* __restrict__ w2,   // (4,4,3,3)  uniform -> s_load
    const float* __restrict__ b2,   // (4,)
    const float* __restrict__ plw,  // (16,196)
    const float* __restrict__ plb,  // (16,)
    const float* __restrict__ rw,   // (4,4)
    const float* __restrict__ rb,   // (4,)
    float* __restrict__ pre,        // (B,4) pre-BN output (in d_out)
    float* __restrict__ stats)      // [8] {sum_c, sumsq_c}
{
  // per-wave h1p: 4 ch x (16 rows x 18 cols) fp32, ch stride 288; data col c
  // at stored c+1 (rows 0,15 / cols 0,15 zero pads persist across iterations).
  __shared__ __align__(16) float h1p[4][4 * 288 + 16];
  // block-shared h2 (bf16): 16 sample slots; 196 data + pad to 224 (K-pad for
  // MFMA) + 8 dummy shorts -> slot stride 232 shorts (464B): 16-lane fragment
  // reads land on 8 distinct banks -> 2-way (free, m136).
  __shared__ __align__(16) u16 h2b[16][232];
  // block-shared transposed bf16 plw in B-fragment layout: row t (kk=8t..8t+7)
  // x 16 params; rows 25..27 zero (K pad to 224).
  __shared__ __align__(16) uint4 plw_tb[28 * 16];
  __shared__ float s_red[4][8];

  const int tid = threadIdx.x;
  const int w = tid >> 6;
  const int lane = tid & 63;
  const int base = (blockIdx.x * 4 + w) * 4;    // first of 4 samples

  // ---- stage plw -> plw_tb (bf16, transposed), once per block ----
  #pragma unroll
  for (int j = 0; j < 2; j++) {
    int s = tid + 256 * j;
    if (s < 448) {
      int tp = s >> 4;                // 0..27
      int k2 = s & 15;
      uint4 v = make_uint4(0u, 0u, 0u, 0u);
      if (tp < 25) {
        const float4* pr = (const float4*)(plw + k2 * 196);
        float4 a = pr[2 * tp];
        float4 b = (tp < 24) ? pr[2 * tp + 1] : make_float4(0.f, 0.f, 0.f, 0.f);
        v = make_uint4(bf2(a.x, a.y), bf2(a.z, a.w),
                       bf2(b.x, b.y), bf2(b.z, b.w));
      }
      plw_tb[s] = v;
    }
  }

  // ---- zero h1p pads + h2b fully (pads persist; data overwritten later) ----
  {
    float4 z4 = make_float4(0.f, 0.f, 0.f, 0.f);
    float4* hz = (float4*)&h1p[w][0];
    #pragma unroll
    for (int t = 0; t < 5; t++) {
      int p = t * 64 + lane;
      if (p < 292) hz[p] = z4;
    }
    uint4 z4u = make_uint4(0u, 0u, 0u, 0u);
    uint4* hz2 = (uint4*)h2b;                   // 16*232 shorts = 464 uint4
    #pragma unroll
    for (int t = 0; t < 2; t++) {
      int p = tid + 256 * t;
      if (p < 464) hz2[p] = z4u;
    }
  }
  __syncthreads();   // plw_tb + h2b zeros visible

  const int i = lane >> 2;            // conv1: pooled row 0..13
  const int q = lane & 3;             // conv1: col quad
  const bool c1act = lane < 56;

  // prefetch buffers for conv1 windows (cols 8q-1 .. 8q+8 fully covered)
  float4 pfa[4], pfb[4];
  float pe0[4], pe1[4];
  #pragma unroll
  for (int r = 0; r < 4; r++) {
    pfa[r] = make_float4(0,0,0,0); pfb[r] = make_float4(0,0,0,0);
    pe0[r] = 0.0f; pe1[r] = 0.0f;
  }

  if (c1act) {
    const float* xb = x + (size_t)base * 784;
    #pragma unroll
    for (int r = 0; r < 4; r++) {
      int row = 2 * i - 1 + r;
      if (0 <= row && row < 28) {
        const float* rp = xb + row * 28;
        pfa[r] = *(const float4*)(rp + 8 * q);
        if (q > 0) pe0[r] = rp[8 * q - 1];
        if (q < 3) {
          pfb[r] = *(const float4*)(rp + 8 * q + 4);
          pe1[r] = rp[8 * q + 8];
        }
      }
    }
  }

  // ================= stage 1: conv both layers for 4 samples =================
  #pragma unroll 1   // rolled: perf-neutral vs unrolled (v14), smaller text
  for (int it = 0; it < 4; ++it) {
    // ---- conv1 + relu + pool ----
    if (c1act) {
      float win[4][10];               // win[r][k] <-> input col 8q-1+k
      #pragma unroll
      for (int r = 0; r < 4; r++) {
        win[r][0] = pe0[r];
        win[r][1] = pfa[r].x; win[r][2] = pfa[r].y;
        win[r][3] = pfa[r].z; win[r][4] = pfa[r].w;
        win[r][5] = pfb[r].x; win[r][6] = pfb[r].y;
        win[r][7] = pfb[r].z; win[r][8] = pfb[r].w;
        win[r][9] = pe1[r];
      }
      // prefetch next sample's rows while conv1 FMAs run
      if (it != 3) {
        const float* xn = x + (size_t)(base + it + 1) * 784;
        #pragma unroll
        for (int r = 0; r < 4; r++) {
          int row = 2 * i - 1 + r;
          pfa[r] = make_float4(0,0,0,0);
          pfb[r] = make_float4(0,0,0,0);
          pe0[r] = 0.0f; pe1[r] = 0.0f;
          if (0 <= row && row < 28) {
            const float* rp = xn + row * 28;
            pfa[r] = *(const float4*)(rp + 8 * q);
            if (q > 0) pe0[r] = rp[8 * q - 1];
            if (q < 3) {
              pfb[r] = *(const float4*)(rp + 8 * q + 4);
              pe1[r] = rp[8 * q + 8];
            }
          }
        }
      }
      v2f P[4][9];
      #pragma unroll
      for (int r = 0; r < 4; r++)
        #pragma unroll
        for (int k = 0; k < 9; k++) P[r][k] = (v2f){win[r][k], win[r][k + 1]};

      float* hb = &h1p[w][18 * (i + 1) + 1 + 4 * q];
      #pragma unroll
      for (int c = 0; c < 4; c++) {
        const float* wc = w1 + c * 9;
        const v2f bias2 = (v2f){b1[c], b1[c]};
        v2f a0[4], a1[4];
        #pragma unroll
        for (int jj = 0; jj < 4; jj++) { a0[jj] = bias2; a1[jj] = bias2; }
        #pragma unroll
        for (int dy = 0; dy < 3; dy++)
          #pragma unroll
          for (int dx = 0; dx < 3; dx++) {
            const float wv = wc[dy * 3 + dx];
            const v2f wvv = (v2f){wv, wv};
            #pragma unroll
            for (int jj = 0; jj < 4; jj++) {
              a0[jj] = pk_fma(P[dy][2 * jj + dx],     wvv, a0[jj]);
              a1[jj] = pk_fma(P[dy + 1][2 * jj + dx], wvv, a1[jj]);
            }
          }
        float m[4];
        #pragma unroll
        for (int jj = 0; jj < 4; jj++) {
          v2f mm = pk_max(a0[jj], a1[jj]);
          m[jj] = fmaxf(fmaxf(mm.x, mm.y), 0.0f);
        }
        float* p = hb + 288 * c;
        if (q < 3) {
          p[0] = m[0];
          *(float2*)(p + 1) = make_float2(m[1], m[2]);
          p[3] = m[3];
        } else {
          p[0] = m[0];
          p[1] = m[1];
        }
      }
    }
    // h1p wave-private: no barrier.

    // ---- conv2 + relu + pool -> h2b[4w+it] (bf16) ----
    {
      const int jq = lane & 7;
      const int i2 = lane >> 3;
      if (i2 < 7 && jq < 7) {
        v2f acc[4][2];
        #pragma unroll
        for (int co = 0; co < 4; co++) {
          const v2f bb = (v2f){b2[co], b2[co]};
          acc[co][0] = bb; acc[co][1] = bb;
        }
        #pragma unroll
        for (int ci = 0; ci < 4; ci++) {
          const float* rp = &h1p[w][288 * ci + 36 * i2 + 2 * jq];
          v2f Q[4][3];
          #pragma unroll
          for (int r = 0; r < 4; r++) {
            v2f a = *(const v2f*)(rp + 18 * r);
            v2f b = *(const v2f*)(rp + 18 * r + 2);
            Q[r][0] = a;
            Q[r][1] = (v2f){a.y, b.x};
            Q[r][2] = b;
          }
          #pragma unroll
          for (int co = 0; co < 4; co++) {
            const float* wp = w2 + (co * 4 + ci) * 9;
            #pragma unroll
            for (int dy = 0; dy < 3; dy++)
              #pragma unroll
              for (int dx = 0; dx < 3; dx++) {
                const float wv = wp[dy * 3 + dx];
                const v2f wvv = (v2f){wv, wv};
                acc[co][0] = pk_fma(Q[dy][dx],     wvv, acc[co][0]);
                acc[co][1] = pk_fma(Q[dy + 1][dx], wvv, acc[co][1]);
              }
          }
        }
        float mo[4];
        #pragma unroll
        for (int co = 0; co < 4; co++) {
          v2f mm = pk_max(acc[co][0], acc[co][1]);
          mo[co] = fmaxf(fmaxf(mm.x, mm.y), 0.0f);
        }
        unsigned u01 = cvtpk(mo[0], mo[1]);
        unsigned u23 = cvtpk(mo[2], mo[3]);
        u16* hp = &h2b[w * 4 + it][7 * i2 + jq];
        hp[0]   = (u16)u01;
        hp[49]  = (u16)(u01 >> 16);
        hp[98]  = (u16)u23;
        hp[147] = (u16)(u23 >> 16);
      }
    }
  }
  __syncthreads();   // h2b complete for all 16 slots

  // ============ stage 2: MFMA linear + circuit for all 4 samples ============
  const int s2 = lane >> 4;           // sample slot 0..3 (within wave)
  const int k = lane & 15;            // param index / amp index

  // ---- linear: 16x224 @ 224x16 bf16 GEMM, 7 MFMA, all waves redundant ----
  float cv, sv;
  {
    const int arow = lane & 15;       // A row = block sample slot, B col = param
    const int kg = lane >> 4;         // k-group 0..3 (8 bf16 each)
    const short8* ha = (const short8*)&h2b[arow][0];    // 29 short8 per slot
    const short8* hbw = (const short8*)plw_tb;
    f32x4 acc = {0.f, 0.f, 0.f, 0.f};
    #pragma unroll
    for (int kt = 0; kt < 7; kt++) {
      short8 av = ha[4 * kt + kg];
      short8 bv = hbw[(4 * kt + kg) * 16 + arow];
      acc = __builtin_amdgcn_mfma_f32_16x16x32_bf16(av, bv, acc, 0, 0, 0);
    }
    // C[row=4*(l>>4)+reg][col=l&15]; wave w needs rows 4w..4w+3 -> quadrant w.
    const int srcl = 16 * w + k;      // lane holding C[4w+*][k]
    float c0 = __shfl(acc[0], srcl, 64);
    float c1 = __shfl(acc[1], srcl, 64);
    float c2 = __shfl(acc[2], srcl, 64);
    float c3 = __shfl(acc[3], srcl, 64);
    float pv = (s2 & 2) ? ((s2 & 1) ? c3 : c2) : ((s2 & 1) ? c1 : c0);
    pv += plb[k];
    __sincosf(pv * 0.5f, &sv, &cv);
  }

  // ---- 4-qubit circuit: 4 samples in parallel on 16-lane groups ----
  {
    const int l = k;                  // amp index within group
    const int gb = lane & 48;         // group base for param broadcasts
    float re = (l == 0) ? 1.0f : 0.0f;
    float im = 0.0f;
    #pragma unroll
    for (int qi = 0; qi < 4; qi++) {
      const int beta = 3 - qi;
      const int m = 1 << beta;        // <16: shfl_xor stays in group
      const int b = (l >> beta) & 1;
      float c = __shfl(cv, gb + 4 * qi, 64), s = __shfl(sv, gb + 4 * qi, 64);
      float pr_ = __shfl_xor(re, m, 64), pi_ = __shfl_xor(im, m, 64);
      float sg = b ? s : -s;
      re = fmaf(c, re, sg * pr_);
      im = fmaf(c, im, sg * pi_);
      c = __shfl(cv, gb + 4 * qi + 1, 64); s = __shfl(sv, gb + 4 * qi + 1, 64);
      float sz = b ? s : -s;
      float nr = c * re - sz * im;
      float ni = c * im + sz * re;
      re = nr; im = ni;
      c = __shfl(cv, gb + 4 * qi + 2, 64); s = __shfl(sv, gb + 4 * qi + 2, 64);
      pr_ = __shfl_xor(re, m, 64); pi_ = __shfl_xor(im, m, 64);
      nr = fmaf(c, re, s * pi_);
      ni = fmaf(c, im, -s * pr_);
      re = nr; im = ni;
      const int tm = 1 << (3 - ((qi + 1) & 3));   // <16: in-group
      float fr = __shfl_xor(re, tm, 64), fi = __shfl_xor(im, tm, 64);
      if (b) { re = fr; im = fi; }
    }
    float pr2 = re * re + im * im;
    float z0 = ((l >> 3) & 1) ? -pr2 : pr2;
    float z1 = ((l >> 2) & 1) ? -pr2 : pr2;
    float z2 = ((l >> 1) & 1) ? -pr2 : pr2;
    float z3 = (l & 1) ? -pr2 : pr2;
    #pragma unroll
    for (int off = 8; off >= 1; off >>= 1) {      // in-group reductions
      z0 += __shfl_xor(z0, off, 64);
      z1 += __shfl_xor(z1, off, 64);
      z2 += __shfl_xor(z2, off, 64);
      z3 += __shfl_xor(z3, off, 64);
    }
    float as0 = 0.f, as1 = 0.f, as2 = 0.f, as3 = 0.f;
    float aq0 = 0.f, aq1 = 0.f, aq2 = 0.f, aq3 = 0.f;
    if (l == 0) {                     // lanes 0,16,32,48: one sample each
      float o0 = fmaf(rw[0],  z0, fmaf(rw[1],  z1, fmaf(rw[2],  z2, fmaf(rw[3],  z3, rb[0]))));
      float o1 = fmaf(rw[4],  z0, fmaf(rw[5],  z1, fmaf(rw[6],  z2, fmaf(rw[7],  z3, rb[1]))));
      float o2 = fmaf(rw[8],  z0, fmaf(rw[9],  z1, fmaf(rw[10], z2, fmaf(rw[11], z3, rb[2]))));
      float o3 = fmaf(rw[12], z0, fmaf(rw[13], z1, fmaf(rw[14], z2, fmaf(rw[15], z3, rb[3]))));
      *(float4*)(pre + (size_t)(base + s2) * 4) = make_float4(o0, o1, o2, o3);
      as0 = o0; aq0 = o0 * o0;
      as1 = o1; aq1 = o1 * o1;
      as2 = o2; aq2 = o2 * o2;
      as3 = o3; aq3 = o3 * o3;
    }
    #pragma unroll
    for (int off = 32; off >= 16; off >>= 1) {
      as0 += __shfl_down(as0, off, 64); aq0 += __shfl_down(aq0, off, 64);
      as1 += __shfl_down(as1, off, 64); aq1 += __shfl_down(aq1, off, 64);
      as2 += __shfl_down(as2, off, 64); aq2 += __shfl_down(aq2, off, 64);
      as3 += __shfl_down(as3, off, 64); aq3 += __shfl_down(aq3, off, 64);
    }
    if (lane == 0) {
      s_red[w][0] = as0; s_red[w][4] = aq0;
      s_red[w][1] = as1; s_red[w][5] = aq1;
      s_red[w][2] = as2; s_red[w][6] = aq2;
      s_red[w][3] = as3; s_red[w][7] = aq3;
    }
  }
  __syncthreads();
  if (tid < 8) {
    float v = s_red[0][tid] + s_red[1][tid] + s_red[2][tid] + s_red[3][tid];
    atomicAdd(&stats[tid], v);
  }
}

__global__ __launch_bounds__(256) void qnat_bn(
    float* __restrict__ pre,
    const float* __restrict__ stats,
    const float* __restrict__ bnw,
    const float* __restrict__ bnb)
{
  int idx = blockIdx.x * 256 + threadIdx.x;
  int c = idx & 3;
  float mean = stats[c] * (1.0f / BATCH);
  float ex2 = stats[4 + c] * (1.0f / BATCH);
  float var = ex2 - mean * mean;
  float inv = rsqrtf(var + 1e-5f);
  pre[idx] = (pre[idx] - mean) * inv * bnw[c] + bnb[c];
}

extern "C" void kernel_launch(void* const* d_in, const int* in_sizes, int n_in,
                              void* d_out, int out_size, void* d_ws, size_t ws_size,
                              hipStream_t stream) {
  const float* x   = (const float*)d_in[0];
  const float* w1  = (const float*)d_in[1];
  const float* b1  = (const float*)d_in[2];
  const float* w2  = (const float*)d_in[3];
  const float* b2  = (const float*)d_in[4];
  const float* plw = (const float*)d_in[5];
  const float* plb = (const float*)d_in[6];
  const float* rw  = (const float*)d_in[7];
  const float* rb  = (const float*)d_in[8];
  const float* bnw = (const float*)d_in[9];
  const float* bnb = (const float*)d_in[10];

  float* out   = (float*)d_out;
  float* stats = (float*)d_ws;

  hipMemsetAsync(stats, 0, 8 * sizeof(float), stream);
  qnat_fused<<<BATCH / 16, 256, 0, stream>>>(x, w1, b1, w2, b2, plw, plb, rw, rb, out, stats);
  qnat_bn<<<(BATCH * 4) / 256, 256, 0, stream>>>(out, stats, bnw, bnb);
}

// Round 5
// 130.371 us; speedup vs baseline: 1.7187x; 1.0170x over previous
//
#include <hip/hip_runtime.h>
#include <math.h>

#define BATCH 16384

typedef float v2f __attribute__((ext_vector_type(2)));
typedef unsigned short u16;
typedef __attribute__((ext_vector_type(8))) short short8;
typedef __attribute__((ext_vector_type(4))) float f32x4;

__device__ __forceinline__ v2f pk_fma(v2f a, v2f b, v2f c) {
  return __builtin_elementwise_fma(a, b, c);   // -> v_pk_fma_f32
}
__device__ __forceinline__ v2f pk_max(v2f a, v2f b) {
  return __builtin_elementwise_max(a, b);      // -> v_pk_max_f32
}

// RNE-pack two floats into a bf16 pair (lo -> low16, hi -> high16)
__device__ __forceinline__ unsigned bf2(float lo, float hi) {
  unsigned a = __float_as_uint(lo);
  unsigned b = __float_as_uint(hi);
  a = (a + 0x7fffu + ((a >> 16) & 1u)) >> 16;
  b = (b + 0x7fffu + ((b >> 16) & 1u)) & 0xffff0000u;
  return a | b;
}

// single-inst RNE pack: dst.lo16 = bf16(lo), dst.hi16 = bf16(hi)
__device__ __forceinline__ unsigned cvtpk(float lo, float hi) {
  unsigned r;
  asm("v_cvt_pk_bf16_f32 %0, %1, %2" : "=v"(r) : "v"(lo), "v"(hi));
  return r;
}

// v16 = v15 + conv2 moved to MFMA (the dominant VALU block: 1152 pk_fma +
// 128 b64 reads/wave). Per pooled position p: M=16 block samples, N=16 =
// (co x 2x2 subpos), K=64 = (ci x 4x4 patch) -> 2x mfma_16x16x32_bf16; 49
// positions split across 4 waves. conv1 writes pooled output straight to a
// block-shared bf16 h1 tile (stride 513 dwords -> 2-way/free fragment gather,
// m136); B = w2 scattered to 64x16 with structural zeros, preloaded to 2
// short8 regs; subpos pooling = 2 shfl_xor (adjacent C columns). Fragment
// conventions identical to the v15-refcheck-verified ones. v15 note: profiled
// machine was downclocked (hbm_gbps 392 vs 552 same bytes) - bench dur_us is
// ground truth (132.59, best).
__global__ __launch_bounds__(256) void qnat_fused(
    const float* __restrict__ x,    // (B,1,28,28)
    const float* __restrict__ w1,   // (4,1,3,3)  uniform -> s_load
    const float* __restrict__ b1,   // (4,)
    const float* __restrict__ w2,   // (4,4,3,3)  uniform -> s_load
    const float* __restrict__ b2,   // (4,)
    const float* __restrict__ plw,  // (16,196)
    const float* __restrict__ plb,  // (16,)
    const float* __restrict__ rw,   // (4,4)
    const float* __restrict__ rb,   // (4,)
    float* __restrict__ pre,        // (B,4) pre-BN output (in d_out)
    float* __restrict__ stats)      // [8] {sum_c, sumsq_c}
{
  // block-shared pooled conv1 output, bf16: per sample 4ci x 16x16 (y,x each
  // offset +1; rows/cols 0,15 zero pads), sample stride 513 dwords (odd ->
  // 16-sample fragment gather hits each bank 2x = free).
  __shared__ __align__(16) unsigned h1sh[16 * 513];
  // block-shared h2 (bf16): 16 slots; 196 data + pad to 224 + 8 -> stride 232
  __shared__ __align__(16) u16 h2b[16][232];
  // transposed bf16 plw in B-fragment layout; rows 25..27 zero (K pad 224)
  __shared__ __align__(16) uint4 plw_tb[28 * 16];
  // conv2 B matrix (64K x 16N) bf16: B[(ci*16+dy*4+dx)*16 + (co*4+sy*2+sx)]
  __shared__ __align__(16) u16 b2f[64 * 16];
  __shared__ float s_red[4][8];

  const int tid = threadIdx.x;
  const int w = tid >> 6;
  const int lane = tid & 63;
  const int base = (blockIdx.x * 4 + w) * 4;    // first of 4 samples

  // ---- stage plw -> plw_tb (bf16, transposed), once per block ----
  #pragma unroll
  for (int j = 0; j < 2; j++) {
    int s = tid + 256 * j;
    if (s < 448) {
      int tp = s >> 4;                // 0..27
      int k2 = s & 15;
      uint4 v = make_uint4(0u, 0u, 0u, 0u);
      if (tp < 25) {
        const float4* pr = (const float4*)(plw + k2 * 196);
        float4 a = pr[2 * tp];
        float4 b = (tp < 24) ? pr[2 * tp + 1] : make_float4(0.f, 0.f, 0.f, 0.f);
        v = make_uint4(bf2(a.x, a.y), bf2(a.z, a.w),
                       bf2(b.x, b.y), bf2(b.z, b.w));
      }
      plw_tb[s] = v;
    }
  }

  // ---- build conv2 B matrix (1024 entries, 4/thread) ----
  #pragma unroll
  for (int j = 0; j < 4; j++) {
    int e = tid + 256 * j;            // e = k*16 + n
    int kk = e >> 4, n = e & 15;
    int ci = kk >> 4, dy = (kk >> 2) & 3, dx = kk & 3;
    int co = n >> 2, sy = (n >> 1) & 1, sx = n & 1;
    int ry = dy - sy, rx = dx - sx;
    float v = 0.0f;
    if (ry >= 0 && ry < 3 && rx >= 0 && rx < 3)
      v = w2[((co * 4 + ci) * 3 + ry) * 3 + rx];
    b2f[e] = (u16)bf2(v, 0.0f);
  }

  // ---- zero h1sh (pads persist; data overwritten) + h2b fully ----
  {
    uint4 z4 = make_uint4(0u, 0u, 0u, 0u);
    uint4* hz = (uint4*)h1sh;                   // 16*513 u32 = 2052 uint4
    #pragma unroll
    for (int t = 0; t < 9; t++) {
      int p = tid + 256 * t;
      if (p < 2052) hz[p] = z4;
    }
    uint4* hz2 = (uint4*)h2b;                   // 16*232 shorts = 464 uint4
    #pragma unroll
    for (int t = 0; t < 2; t++) {
      int p = tid + 256 * t;
      if (p < 464) hz2[p] = z4;
    }
  }
  __syncthreads();   // plw_tb, b2f, zeros visible

  const int i = lane >> 2;            // conv1: pooled row 0..13
  const int q = lane & 3;             // conv1: col quad
  const bool c1act = lane < 56;

  // prefetch buffers for conv1 windows (cols 8q-1 .. 8q+8 fully covered)
  float4 pfa[4], pfb[4];
  float pe0[4], pe1[4];
  #pragma unroll
  for (int r = 0; r < 4; r++) {
    pfa[r] = make_float4(0,0,0,0); pfb[r] = make_float4(0,0,0,0);
    pe0[r] = 0.0f; pe1[r] = 0.0f;
  }

  if (c1act) {
    const float* xb = x + (size_t)base * 784;
    #pragma unroll
    for (int r = 0; r < 4; r++) {
      int row = 2 * i - 1 + r;
      if (0 <= row && row < 28) {
        const float* rp = xb + row * 28;
        pfa[r] = *(const float4*)(rp + 8 * q);
        if (q > 0) pe0[r] = rp[8 * q - 1];
        if (q < 3) {
          pfb[r] = *(const float4*)(rp + 8 * q + 4);
          pe1[r] = rp[8 * q + 8];
        }
      }
    }
  }

  // ================= stage 1a: conv1 for 4 samples -> h1sh (bf16) ============
  #pragma unroll 1
  for (int it = 0; it < 4; ++it) {
    if (c1act) {
      float win[4][10];               // win[r][k] <-> input col 8q-1+k
      #pragma unroll
      for (int r = 0; r < 4; r++) {
        win[r][0] = pe0[r];
        win[r][1] = pfa[r].x; win[r][2] = pfa[r].y;
        win[r][3] = pfa[r].z; win[r][4] = pfa[r].w;
        win[r][5] = pfb[r].x; win[r][6] = pfb[r].y;
        win[r][7] = pfb[r].z; win[r][8] = pfb[r].w;
        win[r][9] = pe1[r];
      }
      // prefetch next sample's rows while conv1 FMAs run
      if (it != 3) {
        const float* xn = x + (size_t)(base + it + 1) * 784;
        #pragma unroll
        for (int r = 0; r < 4; r++) {
          int row = 2 * i - 1 + r;
          pfa[r] = make_float4(0,0,0,0);
          pfb[r] = make_float4(0,0,0,0);
          pe0[r] = 0.0f; pe1[r] = 0.0f;
          if (0 <= row && row < 28) {
            const float* rp = xn + row * 28;
            pfa[r] = *(const float4*)(rp + 8 * q);
            if (q > 0) pe0[r] = rp[8 * q - 1];
            if (q < 3) {
              pfb[r] = *(const float4*)(rp + 8 * q + 4);
              pe1[r] = rp[8 * q + 8];
            }
          }
        }
      }
      v2f P[4][9];
      #pragma unroll
      for (int r = 0; r < 4; r++)
        #pragma unroll
        for (int k = 0; k < 9; k++) P[r][k] = (v2f){win[r][k], win[r][k + 1]};

      // u16 base into h1sh for this sample: stride 1026 u16/sample
      u16* hs = (u16*)h1sh + (4 * w + it) * 1026 + (i + 1) * 16 + 4 * q;
      #pragma unroll
      for (int c = 0; c < 4; c++) {
        const float* wc = w1 + c * 9;
        const v2f bias2 = (v2f){b1[c], b1[c]};
        v2f a0[4], a1[4];
        #pragma unroll
        for (int jj = 0; jj < 4; jj++) { a0[jj] = bias2; a1[jj] = bias2; }
        #pragma unroll
        for (int dy = 0; dy < 3; dy++)
          #pragma unroll
          for (int dx = 0; dx < 3; dx++) {
            const float wv = wc[dy * 3 + dx];
            const v2f wvv = (v2f){wv, wv};
            #pragma unroll
            for (int jj = 0; jj < 4; jj++) {
              a0[jj] = pk_fma(P[dy][2 * jj + dx],     wvv, a0[jj]);
              a1[jj] = pk_fma(P[dy + 1][2 * jj + dx], wvv, a1[jj]);
            }
          }
        float m[4];
        #pragma unroll
        for (int jj = 0; jj < 4; jj++) {
          v2f mm = pk_max(a0[jj], a1[jj]);
          m[jj] = fmaxf(fmaxf(mm.x, mm.y), 0.0f);
        }
        u16* p = hs + c * 256;        // stored cols 4q+1 .. 4q+4 (x offset +1)
        p[1] = (u16)cvtpk(m[0], m[0]);
        if (q < 3) {
          *(unsigned*)(p + 2) = cvtpk(m[1], m[2]);   // even u16 idx -> 4B align
          p[4] = (u16)cvtpk(m[3], m[3]);
        } else {
          p[2] = (u16)cvtpk(m[1], m[1]);
        }
      }
    }
  }
  __syncthreads();   // h1sh complete for all 16 samples

  // ======== stage 1b: conv2 + relu + pool via MFMA -> h2b (bf16) ============
  {
    const int n = lane & 15;          // A row = sample, B/C col = (co,sy,sx)
    const int g = lane >> 4;          // k-group
    // preload B fragments (k = 32*kt + 8g + j)
    short8 bfr0, bfr1;
    #pragma unroll
    for (int j = 0; j < 8; j++) {
      bfr0[j] = (short)b2f[(8 * g + j) * 16 + n];
      bfr1[j] = (short)b2f[(32 + 8 * g + j) * 16 + n];
    }
    const float b2v = b2[n >> 2];
    const int ci0 = g >> 1;
    const int dy0 = 2 * (g & 1);
    const int dbase = n * 513 + ci0 * 128 + dy0 * 8;   // dwords
    const unsigned* hp = h1sh;

    #pragma unroll 2
    for (int t = 0; t < 13; t++) {
      int p = 4 * t + w;              // wave-strided positions
      if (p < 49) {
        int i2 = (p * 9363) >> 16;    // p/7
        int j2 = p - 7 * i2;
        int d = dbase + i2 * 16 + j2;
        f32x4 acc = {0.f, 0.f, 0.f, 0.f};
        {
          unsigned A0 = hp[d],       A1 = hp[d + 1];
          unsigned A2 = hp[d + 8],   A3 = hp[d + 9];
          short8 av = __builtin_bit_cast(short8, make_uint4(A0, A1, A2, A3));
          acc = __builtin_amdgcn_mfma_f32_16x16x32_bf16(av, bfr0, acc, 0, 0, 0);
        }
        {
          unsigned A0 = hp[d + 256], A1 = hp[d + 257];
          unsigned A2 = hp[d + 264], A3 = hp[d + 265];
          short8 av = __builtin_bit_cast(short8, make_uint4(A0, A1, A2, A3));
          acc = __builtin_amdgcn_mfma_f32_16x16x32_bf16(av, bfr1, acc, 0, 0, 0);
        }
        // pool over subpos: cols n^1 (sx), n^2 (sy) -> lanes lane^1, lane^2
        float r0 = acc[0], r1 = acc[1], r2 = acc[2], r3 = acc[3];
        r0 = fmaxf(r0, __shfl_xor(r0, 1, 64)); r0 = fmaxf(r0, __shfl_xor(r0, 2, 64));
        r1 = fmaxf(r1, __shfl_xor(r1, 1, 64)); r1 = fmaxf(r1, __shfl_xor(r1, 2, 64));
        r2 = fmaxf(r2, __shfl_xor(r2, 1, 64)); r2 = fmaxf(r2, __shfl_xor(r2, 2, 64));
        r3 = fmaxf(r3, __shfl_xor(r3, 1, 64)); r3 = fmaxf(r3, __shfl_xor(r3, 2, 64));
        if ((lane & 3) == 0) {
          int co = n >> 2;
          u16* hq = &h2b[4 * g][49 * co + p];
          float v0 = fmaxf(r0 + b2v, 0.0f);
          float v1 = fmaxf(r1 + b2v, 0.0f);
          float v2 = fmaxf(r2 + b2v, 0.0f);
          float v3 = fmaxf(r3 + b2v, 0.0f);
          hq[0]       = (u16)cvtpk(v0, v0);   // sample 4g+0
          hq[232]     = (u16)cvtpk(v1, v1);   // sample 4g+1
          hq[464]     = (u16)cvtpk(v2, v2);   // sample 4g+2
          hq[696]     = (u16)cvtpk(v3, v3);   // sample 4g+3
        }
      }
    }
  }
  __syncthreads();   // h2b complete for all 16 slots

  // ============ stage 2: MFMA linear + circuit for all 4 samples ============
  const int s2 = lane >> 4;           // sample slot 0..3 (within wave)
  const int k = lane & 15;            // param index / amp index

  // ---- linear: 16x224 @ 224x16 bf16 GEMM, 7 MFMA, all waves redundant ----
  float cv, sv;
  {
    const int arow = lane & 15;       // A row = block sample slot, B col = param
    const int kg = lane >> 4;         // k-group 0..3 (8 bf16 each)
    const short8* ha = (const short8*)&h2b[arow][0];    // 29 short8 per slot
    const short8* hbw = (const short8*)plw_tb;
    f32x4 acc = {0.f, 0.f, 0.f, 0.f};
    #pragma unroll
    for (int kt = 0; kt < 7; kt++) {
      short8 av = ha[4 * kt + kg];
      short8 bv = hbw[(4 * kt + kg) * 16 + arow];
      acc = __builtin_amdgcn_mfma_f32_16x16x32_bf16(av, bv, acc, 0, 0, 0);
    }
    // C[row=4*(l>>4)+reg][col=l&15]; wave w needs rows 4w..4w+3 -> quadrant w.
    const int srcl = 16 * w + k;      // lane holding C[4w+*][k]
    float c0 = __shfl(acc[0], srcl, 64);
    float c1 = __shfl(acc[1], srcl, 64);
    float c2 = __shfl(acc[2], srcl, 64);
    float c3 = __shfl(acc[3], srcl, 64);
    float pv = (s2 & 2) ? ((s2 & 1) ? c3 : c2) : ((s2 & 1) ? c1 : c0);
    pv += plb[k];
    __sincosf(pv * 0.5f, &sv, &cv);
  }

  // ---- 4-qubit circuit: 4 samples in parallel on 16-lane groups ----
  {
    const int l = k;                  // amp index within group
    const int gb = lane & 48;         // group base for param broadcasts
    float re = (l == 0) ? 1.0f : 0.0f;
    float im = 0.0f;
    #pragma unroll
    for (int qi = 0; qi < 4; qi++) {
      const int beta = 3 - qi;
      const int m = 1 << beta;        // <16: shfl_xor stays in group
      const int b = (l >> beta) & 1;
      float c = __shfl(cv, gb + 4 * qi, 64), s = __shfl(sv, gb + 4 * qi, 64);
      float pr_ = __shfl_xor(re, m, 64), pi_ = __shfl_xor(im, m, 64);
      float sg = b ? s : -s;
      re = fmaf(c, re, sg * pr_);
      im = fmaf(c, im, sg * pi_);
      c = __shfl(cv, gb + 4 * qi + 1, 64); s = __shfl(sv, gb + 4 * qi + 1, 64);
      float sz = b ? s : -s;
      float nr = c * re - sz * im;
      float ni = c * im + sz * re;
      re = nr; im = ni;
      c = __shfl(cv, gb + 4 * qi + 2, 64); s = __shfl(sv, gb + 4 * qi + 2, 64);
      pr_ = __shfl_xor(re, m, 64); pi_ = __shfl_xor(im, m, 64);
      nr = fmaf(c, re, s * pi_);
      ni = fmaf(c, im, -s * pr_);
      re = nr; im = ni;
      const int tm = 1 << (3 - ((qi + 1) & 3));   // <16: in-group
      float fr = __shfl_xor(re, tm, 64), fi = __shfl_xor(im, tm, 64);
      if (b) { re = fr; im = fi; }
    }
    float pr2 = re * re + im * im;
    float z0 = ((l >> 3) & 1) ? -pr2 : pr2;
    float z1 = ((l >> 2) & 1) ? -pr2 : pr2;
    float z2 = ((l >> 1) & 1) ? -pr2 : pr2;
    float z3 = (l & 1) ? -pr2 : pr2;
    #pragma unroll
    for (int off = 8; off >= 1; off >>= 1) {      // in-group reductions
      z0 += __shfl_xor(z0, off, 64);
      z1 += __shfl_xor(z1, off, 64);
      z2 += __shfl_xor(z2, off, 64);
      z3 += __shfl_xor(z3, off, 64);
    }
    float as0 = 0.f, as1 = 0.f, as2 = 0.f, as3 = 0.f;
    float aq0 = 0.f, aq1 = 0.f, aq2 = 0.f, aq3 = 0.f;
    if (l == 0) {                     // lanes 0,16,32,48: one sample each
      float o0 = fmaf(rw[0],  z0, fmaf(rw[1],  z1, fmaf(rw[2],  z2, fmaf(rw[3],  z3, rb[0]))));
      float o1 = fmaf(rw[4],  z0, fmaf(rw[5],  z1, fmaf(rw[6],  z2, fmaf(rw[7],  z3, rb[1]))));
      float o2 = fmaf(rw[8],  z0, fmaf(rw[9],  z1, fmaf(rw[10], z2, fmaf(rw[11], z3, rb[2]))));
      float o3 = fmaf(rw[12], z0, fmaf(rw[13], z1, fmaf(rw[14], z2, fmaf(rw[15], z3, rb[3]))));
      *(float4*)(pre + (size_t)(base + s2) * 4) = make_float4(o0, o1, o2, o3);
      as0 = o0; aq0 = o0 * o0;
      as1 = o1; aq1 = o1 * o1;
      as2 = o2; aq2 = o2 * o2;
      as3 = o3; aq3 = o3 * o3;
    }
    #pragma unroll
    for (int off = 32; off >= 16; off >>= 1) {
      as0 += __shfl_down(as0, off, 64); aq0 += __shfl_down(aq0, off, 64);
      as1 += __shfl_down(as1, off, 64); aq1 += __shfl_down(aq1, off, 64);
      as2 += __shfl_down(as2, off, 64); aq2 += __shfl_down(aq2, off, 64);
      as3 += __shfl_down(as3, off, 64); aq3 += __shfl_down(aq3, off, 64);
    }
    if (lane == 0) {
      s_red[w][0] = as0; s_red[w][4] = aq0;
      s_red[w][1] = as1; s_red[w][5] = aq1;
      s_red[w][2] = as2; s_red[w][6] = aq2;
      s_red[w][3] = as3; s_red[w][7] = aq3;
    }
  }
  __syncthreads();
  if (tid < 8) {
    float v = s_red[0][tid] + s_red[1][tid] + s_red[2][tid] + s_red[3][tid];
    atomicAdd(&stats[tid], v);
  }
}

__global__ __launch_bounds__(256) void qnat_bn(
    float* __restrict__ pre,
    const float* __restrict__ stats,
    const float* __restrict__ bnw,
    const float* __restrict__ bnb)
{
  int idx = blockIdx.x * 256 + threadIdx.x;
  int c = idx & 3;
  float mean = stats[c] * (1.0f / BATCH);
  float ex2 = stats[4 + c] * (1.0f / BATCH);
  float var = ex2 - mean * mean;
  float inv = rsqrtf(var + 1e-5f);
  pre[idx] = (pre[idx] - mean) * inv * bnw[c] + bnb[c];
}

extern "C" void kernel_launch(void* const* d_in, const int* in_sizes, int n_in,
                              void* d_out, int out_size, void* d_ws, size_t ws_size,
                              hipStream_t stream) {
  const float* x   = (const float*)d_in[0];
  const float* w1  = (const float*)d_in[1];
  const float* b1  = (const float*)d_in[2];
  const float* w2  = (const float*)d_in[3];
  const float* b2  = (const float*)d_in[4];
  const float* plw = (const float*)d_in[5];
  const float* plb = (const float*)d_in[6];
  const float* rw  = (const float*)d_in[7];
  const float* rb  = (const float*)d_in[8];
  const float* bnw = (const float*)d_in[9];
  const float* bnb = (const float*)d_in[10];

  float* out   = (float*)d_out;
  float* stats = (float*)d_ws;

  hipMemsetAsync(stats, 0, 8 * sizeof(float), stream);
  qnat_fused<<<BATCH / 16, 256, 0, stream>>>(x, w1, b1, w2, b2, plw, plb, rw, rb, out, stats);
  qnat_bn<<<(BATCH * 4) / 256, 256, 0, stream>>>(out, stats, bnw, bnb);
}